// Round 7
// baseline (195.788 us; speedup 1.0000x reference)
//
#include <hip/hip_runtime.h>
#include <hip/hip_bf16.h>
#include <stdint.h>

#define N_NODES 20000
#define N_EDGES 640000
#define FEAT 128
#define CAPD 128      // per-dst list cap; deg ~ Poisson(32), P(>128) ~ 1e-43
#define NPHASE 8      // o-feature slices of 16 (2.56 MB h-slice, L2-resident per XCD)
#define CNTSTRIDE 16  // one counter per 64B line: no same-line atomic serialization

typedef __attribute__((ext_vector_type(8))) short bf16x8;
typedef __attribute__((ext_vector_type(4))) float f32x4;

// ---------- helpers ----------
// packed f32x2 -> bf16x2 (v_cvt_pk_bf16_f32), lo in low half
__device__ __forceinline__ unsigned pkbf16(float lo, float hi) {
  __hip_bfloat162 p = __float22bfloat162_rn(make_float2(lo, hi));
  return *reinterpret_cast<unsigned*>(&p);
}

// order-preserving encode: f32 -> RNE-rounded bf16 -> monotone u16
__device__ __forceinline__ unsigned short enc16(float f) {
  unsigned a = __float_as_uint(f);
  unsigned b = (a + 0x7FFFu + ((a >> 16) & 1u)) >> 16;  // RNE to bf16
  unsigned s = (unsigned)((int)a >> 31);                // 0 or ~0
  return (unsigned short)((b ^ 0x8000u) ^ (s & 0x7FFFu));
}

// inverse of enc16 (result as f32)
__device__ __forceinline__ float dec16(unsigned e) {
  unsigned b = (e & 0x8000u) ? (e ^ 0x8000u) : (e ^ 0xFFFFu);
  return __uint_as_float(b << 16);
}

// packed 2x u16 max
__device__ __forceinline__ void pmax(unsigned& a, unsigned v) {
  asm("v_pk_max_u16 %0, %0, %1" : "+v"(a) : "v"(v));
}

#define PMX4(v)                                              \
  do {                                                       \
    pmax(a0, (v).x); pmax(a1, (v).y);                        \
    pmax(a2, (v).z); pmax(a3, (v).w);                        \
  } while (0)

// ---------- kernel 1: zero padded cnt + convert W -> bf16 ([o][f] layout) ----------
__global__ void init_kernel(const float* __restrict__ W,
                            unsigned short* __restrict__ Wbf,
                            int* __restrict__ cnt) {
  int i = blockIdx.x * 256 + threadIdx.x;
  if (i < N_NODES * CNTSTRIDE) cnt[i] = 0;
  if (i < FEAT * FEAT / 2) {
    float2 w = ((const float2*)W)[i];
    ((unsigned*)Wbf)[i] = pkbf16(w.x, w.y);
  }
}

// ---------- kernel 2: FUSED edge scatter + MFMA GEMM (enc16-encoded h) ----------
// Scatter first: the 2 atomic chains per thread issue before x-staging, and
// their ~700-cycle latency hides under staging loads + MFMA of co-resident
// blocks (R1 evidence: fused = 73 us vs ~90 us split).
__global__ __launch_bounds__(256) void gemm_scatter_kernel(
    const float4* __restrict__ x, const unsigned short* __restrict__ Wbf,
    const float* __restrict__ b, uint4* __restrict__ h,
    const int* __restrict__ ei, int* __restrict__ cnt,
    unsigned short* __restrict__ csr) {
  // x-stage: [t][16 n][136 f] bf16 = 17408 B.  h-stage (aliased): [16 n][520] u16.
  __shared__ __align__(16) unsigned short sm[17408 / 2];
  const int tid = threadIdx.x;
  const int n0 = blockIdx.x * 16;

  // ---- scatter: 512 edges per block into per-dst lists (padded counters) ----
#pragma unroll
  for (int r = 0; r < 2; ++r) {
    int e = blockIdx.x * 512 + r * 256 + tid;
    int src = ei[e];
    int dst = ei[N_EDGES + e];
    int pos = atomicAdd(&cnt[dst * CNTSTRIDE], 1);
    if (pos < CAPD) csr[(size_t)dst * CAPD + pos] = (unsigned short)src;
  }

  // ---- stage x -> LDS bf16 [t][n][f] via v_cvt_pk_bf16_f32 ----
#pragma unroll
  for (int it = 0; it < 4; ++it) {
    int e = tid + it * 256;       // 16 n x 64 f-pairs
    int n = e >> 6, fp = e & 63;  // f = 2*fp
    float4 a = x[(size_t)(n0 + n) * 128 + 2 * fp];
    float4 c = x[(size_t)(n0 + n) * 128 + 2 * fp + 1];
    ((unsigned*)sm)[(0 * 16 + n) * 68 + fp] = pkbf16(a.x, c.x);
    ((unsigned*)sm)[(1 * 16 + n) * 68 + fp] = pkbf16(a.y, c.y);
    ((unsigned*)sm)[(2 * 16 + n) * 68 + fp] = pkbf16(a.z, c.z);
    ((unsigned*)sm)[(3 * 16 + n) * 68 + fp] = pkbf16(a.w, c.w);
  }

  __syncthreads();

  const int wv = tid >> 6;  // t
  const int l = tid & 63;
  const int col = l & 15;
  const int quad = l >> 4;

  f32x4 acc[8];
#pragma unroll
  for (int os = 0; os < 8; ++os) {
    float bv = b[os * 16 + col];
    acc[os] = (f32x4){bv, bv, bv, bv};
  }

#pragma unroll
  for (int k = 0; k < 4; ++k) {
    bf16x8 af = *(const bf16x8*)&sm[(wv * 16 + col) * 136 + k * 32 + quad * 8];
#pragma unroll
    for (int os = 0; os < 8; ++os) {
      bf16x8 bfv = *(const bf16x8*)&Wbf[(os * 16 + col) * 128 + k * 32 + quad * 8];
      acc[os] = __builtin_amdgcn_mfma_f32_16x16x32_bf16(af, bfv, acc[os], 0, 0, 0);
    }
  }

  __syncthreads();

  // C layout: D[m = quad*4 + r][o = os*16 + col]; h-stage LDS [n][o][t], row 520 u16.
#pragma unroll
  for (int os = 0; os < 8; ++os) {
#pragma unroll
    for (int r = 0; r < 4; ++r) {
      sm[(quad * 4 + r) * 520 + (os * 16 + col) * 4 + wv] = enc16(acc[os][r]);
    }
  }
  __syncthreads();

#pragma unroll
  for (int it = 0; it < 4; ++it) {
    int e = tid + it * 256;
    int n = e >> 6, q = e & 63;
    uint4 v = *(const uint4*)&sm[n * 520 + q * 8];
    h[(size_t)(n0 + n) * 64 + q] = v;
  }
}

// ---------- kernel 3: o-phased agg, 8 dsts/wave, LDS idx, ping-pong pipeline ----------
// phase = blockIdx.x & 7 == XCD: 2.56 MB h-slice stays L2-resident per XCD.
// Lane (g, oq) owns dst g's 16 B o-slice; indices staged in LDS. Inner loop is
// a ping-pong of two 8-load batches: issue B, pmax A, issue A', pmax B --
// 8 gathers ALWAYS in flight under each pmax block (R6 had VGPR=28: compiler
// had serialized the loads). dmax rounded to 16; clamped lanes re-load entry 0.
#define CLAMP8(P, ivv, base)                                            \
  int P##0 = ((base) + 0 < deg) ? (int)((ivv).x & 0xFFFFu) : idx0;      \
  int P##1 = ((base) + 1 < deg) ? (int)((ivv).x >> 16) : idx0;          \
  int P##2 = ((base) + 2 < deg) ? (int)((ivv).y & 0xFFFFu) : idx0;      \
  int P##3 = ((base) + 3 < deg) ? (int)((ivv).y >> 16) : idx0;          \
  int P##4 = ((base) + 4 < deg) ? (int)((ivv).z & 0xFFFFu) : idx0;      \
  int P##5 = ((base) + 5 < deg) ? (int)((ivv).z >> 16) : idx0;          \
  int P##6 = ((base) + 6 < deg) ? (int)((ivv).w & 0xFFFFu) : idx0;      \
  int P##7 = ((base) + 7 < deg) ? (int)((ivv).w >> 16) : idx0;

#define ISSUE8(V, P)                                                    \
  V##0 = *(const uint4*)(hb + (((unsigned)P##0 << 10) + pb));           \
  V##1 = *(const uint4*)(hb + (((unsigned)P##1 << 10) + pb));           \
  V##2 = *(const uint4*)(hb + (((unsigned)P##2 << 10) + pb));           \
  V##3 = *(const uint4*)(hb + (((unsigned)P##3 << 10) + pb));           \
  V##4 = *(const uint4*)(hb + (((unsigned)P##4 << 10) + pb));           \
  V##5 = *(const uint4*)(hb + (((unsigned)P##5 << 10) + pb));           \
  V##6 = *(const uint4*)(hb + (((unsigned)P##6 << 10) + pb));           \
  V##7 = *(const uint4*)(hb + (((unsigned)P##7 << 10) + pb));

#define PMAX8(V)                                                        \
  do {                                                                  \
    PMX4(V##0); PMX4(V##1); PMX4(V##2); PMX4(V##3);                     \
    PMX4(V##4); PMX4(V##5); PMX4(V##6); PMX4(V##7);                     \
  } while (0)

__global__ __launch_bounds__(256, 4) void agg_kernel(
    const uint4* __restrict__ h, const int* __restrict__ cnt,
    const unsigned short* __restrict__ csr, float4* __restrict__ out) {
  __shared__ __align__(16) unsigned short sidx[32][136];  // 8704 B, row-padded
  const int bid = blockIdx.x;  // 5000 blocks = 625 grp x 8 phases
  const int p = bid & 7;
  const int grp = bid >> 3;
  const int n0 = grp * 32;
  const int tid = threadIdx.x;

  // stage 32 csr rows -> LDS (each thread copies 2x uint4 = 32 B, coalesced)
  {
    int r = tid >> 3;  // 0..31
    int q = tid & 7;   // 0..7
    const uint4* srow = (const uint4*)(csr + (size_t)(n0 + r) * CAPD);
    *(uint4*)&sidx[r][q * 8] = srow[q];
    *(uint4*)&sidx[r][(q + 8) * 8] = srow[q + 8];
  }
  __syncthreads();

  const int w = tid >> 6;
  const int lane = tid & 63;
  const int g = lane >> 3;       // dst slot within wave
  const int oq = lane & 7;       // o-pair slot (2 o x 4 t = 16 B)
  const int n = n0 + w * 8 + g;  // this lane's dst

  int deg = cnt[n * CNTSTRIDE];
  deg = deg > CAPD ? CAPD : deg;

  const unsigned short* myrow = sidx[w * 8 + g];
  int idx0 = (deg > 0) ? (int)myrow[0] : 0;  // clamp target (valid & L1-hot)

  // wave-max of deg (uniform loop bound; clamped lanes load dups)
  int dmax = deg;
#pragma unroll
  for (int d = 8; d <= 32; d <<= 1) {
    int o = __shfl_xor(dmax, d);
    dmax = o > dmax ? o : dmax;
  }
  dmax = __builtin_amdgcn_readfirstlane(dmax);

  unsigned a0 = 0x007F007Fu, a1 = a0, a2 = a0, a3 = a0;  // enc(-inf) packed
  const char* hb = (const char*)h;
  const unsigned pb = (((unsigned)p * 8 + oq) << 4);  // byte offset within h row

  if (dmax > 0) {
    const int dmax16 = (dmax + 15) & ~15;  // 16..128
    uint4 vA0, vA1, vA2, vA3, vA4, vA5, vA6, vA7;
    uint4 vB0, vB1, vB2, vB3, vB4, vB5, vB6, vB7;
    {
      uint4 iv = *(const uint4*)&myrow[0];
      CLAMP8(eA, iv, 0);
      ISSUE8(vA, eA);
    }
    int jb = 0;
    while (true) {
      {
        uint4 iv = *(const uint4*)&myrow[jb + 8];
        CLAMP8(eB, iv, jb + 8);
        ISSUE8(vB, eB);
      }
      PMAX8(vA);
      jb += 16;
      if (jb >= dmax16) {
        PMAX8(vB);
        break;
      }
      {
        uint4 iv = *(const uint4*)&myrow[jb];
        CLAMP8(eA2, iv, jb);
        ISSUE8(vA, eA2);
      }
      PMAX8(vB);
    }
  }

  float4 o0, o1;
  if (deg == 0) {
    o0 = make_float4(0.f, 0.f, 0.f, 0.f);
    o1 = o0;
  } else {
    o0 = make_float4(dec16(a0 & 0xFFFFu), dec16(a0 >> 16),
                     dec16(a1 & 0xFFFFu), dec16(a1 >> 16));
    o1 = make_float4(dec16(a2 & 0xFFFFu), dec16(a2 >> 16),
                     dec16(a3 & 0xFFFFu), dec16(a3 >> 16));
  }
  out[(size_t)n * 128 + p * 16 + oq * 2] = o0;
  out[(size_t)n * 128 + p * 16 + oq * 2 + 1] = o1;
}

// ---------- launcher ----------
extern "C" void kernel_launch(void* const* d_in, const int* in_sizes, int n_in,
                              void* d_out, int out_size, void* d_ws, size_t ws_size,
                              hipStream_t stream) {
  const float* x = (const float*)d_in[0];
  const int* ei = (const int*)d_in[1];
  const float* W = (const float*)d_in[2];
  const float* b = (const float*)d_in[3];
  float* out = (float*)d_out;

  char* ws = (char*)d_ws;
  uint4* h = (uint4*)ws;                                   // 20,480,000 B
  int* cnt = (int*)(ws + 20480000);                        // 20,000 x 16 x 4 = 1,280,000 B
  unsigned short* csr = (unsigned short*)(ws + 21760000);  // 20000*128*2 = 5,120,000 B
  unsigned short* Wbf = (unsigned short*)(ws + 26880000);  // 32,768 B

  init_kernel<<<(N_NODES * CNTSTRIDE + 255) / 256, 256, 0, stream>>>(W, Wbf, cnt);
  gemm_scatter_kernel<<<N_NODES / 16, 256, 0, stream>>>((const float4*)x, Wbf, b, h,
                                                        ei, cnt, csr);
  agg_kernel<<<(N_NODES / 32) * NPHASE, 256, 0, stream>>>(h, cnt, csr, (float4*)out);
}

// Round 8
// 180.581 us; speedup vs baseline: 1.0842x; 1.0842x over previous
//
#include <hip/hip_runtime.h>
#include <hip/hip_bf16.h>
#include <stdint.h>

#define N_NODES 20000
#define N_EDGES 640000
#define FEAT 128
#define CAPD 128      // per-dst list cap; deg ~ Poisson(32), P(>128) ~ 1e-43
#define NPHASE 8      // o-feature slices of 16 (2.56 MB h-slice, L2-resident per XCD)
#define CNTSTRIDE 16  // one counter per 64B line

typedef __attribute__((ext_vector_type(8))) short bf16x8;
typedef __attribute__((ext_vector_type(4))) float f32x4;

// ---------- helpers ----------
// packed f32x2 -> bf16x2 (v_cvt_pk_bf16_f32), lo in low half
__device__ __forceinline__ unsigned pkbf16(float lo, float hi) {
  __hip_bfloat162 p = __float22bfloat162_rn(make_float2(lo, hi));
  return *reinterpret_cast<unsigned*>(&p);
}

// order-preserving encode: f32 -> RNE-rounded bf16 -> monotone u16
__device__ __forceinline__ unsigned short enc16(float f) {
  unsigned a = __float_as_uint(f);
  unsigned b = (a + 0x7FFFu + ((a >> 16) & 1u)) >> 16;  // RNE to bf16
  unsigned s = (unsigned)((int)a >> 31);                // 0 or ~0
  return (unsigned short)((b ^ 0x8000u) ^ (s & 0x7FFFu));
}

// inverse of enc16 (result as f32)
__device__ __forceinline__ float dec16(unsigned e) {
  unsigned b = (e & 0x8000u) ? (e ^ 0x8000u) : (e ^ 0xFFFFu);
  return __uint_as_float(b << 16);
}

// packed 2x u16 max
__device__ __forceinline__ void pmax(unsigned& a, unsigned v) {
  asm("v_pk_max_u16 %0, %0, %1" : "+v"(a) : "v"(v));
}

#define PMX4(v)                                              \
  do {                                                       \
    pmax(a0, (v).x); pmax(a1, (v).y);                        \
    pmax(a2, (v).z); pmax(a3, (v).w);                        \
  } while (0)

// ---------- kernel 1: zero padded cnt + convert W -> bf16 ([o][f] layout) ----------
__global__ void init_kernel(const float* __restrict__ W,
                            unsigned short* __restrict__ Wbf,
                            int* __restrict__ cnt) {
  int i = blockIdx.x * 256 + threadIdx.x;
  if (i < N_NODES * CNTSTRIDE) cnt[i] = 0;
  if (i < FEAT * FEAT / 2) {
    float2 w = ((const float2*)W)[i];
    ((unsigned*)Wbf)[i] = pkbf16(w.x, w.y);
  }
}

// ---------- kernel 2: FUSED scatter + GEMM, 512 threads (8 waves) ----------
// Issue order per thread: {2 ei loads, 4 staging float4, 1 atomicAdd}.
// In-order vmcnt drain => bf16 conversions run at vmcnt(1) (atomic still in
// flight); only the 2B csr store waits vmcnt(0). 8 waves/block at VGPR<=64
// -> ~32 waves/CU: 2x the outstanding atomics of the R7 version, which is
// what a ~900-cycle atomic round trip needs. Waves 4-7 skip MFMA but help
// stage x and write h (pass through barriers).
__global__ __launch_bounds__(512) void gemm_scatter_kernel(
    const float4* __restrict__ x, const unsigned short* __restrict__ Wbf,
    const float* __restrict__ b, uint4* __restrict__ h,
    const int* __restrict__ ei, int* __restrict__ cnt,
    unsigned short* __restrict__ csr) {
  // x-stage: [t][16 n][136 f] bf16 = 17408 B.  h-stage (aliased): [16 n][520] u16.
  __shared__ __align__(16) unsigned short sm[17408 / 2];
  const int tid = threadIdx.x;  // 0..511
  const int n0 = blockIdx.x * 16;

  // ---- edge loads first (oldest in the vmcnt queue) ----
  const int eid = blockIdx.x * 512 + tid;
  int src = ei[eid];
  int dst = ei[N_EDGES + eid];

  // ---- staging loads: 4x float4 per thread (2 f-pair units) ----
  const int e0 = tid, e1 = tid + 512;
  const int na = e0 >> 6, fa = e0 & 63;
  const int nb = e1 >> 6, fb = e1 & 63;
  float4 a0 = x[(size_t)(n0 + na) * 128 + 2 * fa];
  float4 c0 = x[(size_t)(n0 + na) * 128 + 2 * fa + 1];
  float4 a1 = x[(size_t)(n0 + nb) * 128 + 2 * fb];
  float4 c1 = x[(size_t)(n0 + nb) * 128 + 2 * fb + 1];

  // ---- atomic (newest; its latency hides under the conversions below) ----
  int pos = atomicAdd(&cnt[dst * CNTSTRIDE], 1);

  // ---- conversions -> LDS (need staging only: vmcnt(1)) ----
  ((unsigned*)sm)[(0 * 16 + na) * 68 + fa] = pkbf16(a0.x, c0.x);
  ((unsigned*)sm)[(1 * 16 + na) * 68 + fa] = pkbf16(a0.y, c0.y);
  ((unsigned*)sm)[(2 * 16 + na) * 68 + fa] = pkbf16(a0.z, c0.z);
  ((unsigned*)sm)[(3 * 16 + na) * 68 + fa] = pkbf16(a0.w, c0.w);
  ((unsigned*)sm)[(0 * 16 + nb) * 68 + fb] = pkbf16(a1.x, c1.x);
  ((unsigned*)sm)[(1 * 16 + nb) * 68 + fb] = pkbf16(a1.y, c1.y);
  ((unsigned*)sm)[(2 * 16 + nb) * 68 + fb] = pkbf16(a1.z, c1.z);
  ((unsigned*)sm)[(3 * 16 + nb) * 68 + fb] = pkbf16(a1.w, c1.w);

  // ---- csr placement store (waits the atomic: vmcnt(0)) ----
  if (pos < CAPD) csr[(size_t)dst * CAPD + pos] = (unsigned short)src;

  __syncthreads();

  const int wv = tid >> 6;  // wave id; waves 0..3 own t=wv
  const int l = tid & 63;
  const int col = l & 15;
  const int quad = l >> 4;

  if (wv < 4) {
    f32x4 acc[8];
#pragma unroll
    for (int os = 0; os < 8; ++os) {
      float bv = b[os * 16 + col];
      acc[os] = (f32x4){bv, bv, bv, bv};
    }

#pragma unroll
    for (int k = 0; k < 4; ++k) {
      bf16x8 af = *(const bf16x8*)&sm[(wv * 16 + col) * 136 + k * 32 + quad * 8];
#pragma unroll
      for (int os = 0; os < 8; ++os) {
        bf16x8 bfv = *(const bf16x8*)&Wbf[(os * 16 + col) * 128 + k * 32 + quad * 8];
        acc[os] = __builtin_amdgcn_mfma_f32_16x16x32_bf16(af, bfv, acc[os], 0, 0, 0);
      }
    }

    __syncthreads();  // staging reads done; sm can be overwritten

    // C layout: D[m = quad*4 + r][o = os*16 + col]; h-stage LDS [n][o][t], row 520 u16.
#pragma unroll
    for (int os = 0; os < 8; ++os) {
#pragma unroll
      for (int r = 0; r < 4; ++r) {
        sm[(quad * 4 + r) * 520 + (os * 16 + col) * 4 + wv] = enc16(acc[os][r]);
      }
    }
  } else {
    __syncthreads();  // match barrier 2
  }
  __syncthreads();

  // h-write: 2 uint4 per thread across all 8 waves
#pragma unroll
  for (int it = 0; it < 2; ++it) {
    int e = tid + it * 512;
    int n = e >> 6, q = e & 63;
    uint4 v = *(const uint4*)&sm[n * 520 + q * 8];
    h[(size_t)(n0 + n) * 64 + q] = v;
  }
}

// ---------- kernel 3: o-phased agg (R6 body), 8 dsts/wave, LDS-staged idx ----------
// phase = blockIdx.x & 7 == XCD: 2.56 MB h-slice stays L2-resident per XCD.
// Lane (g = lane>>3, oq = lane&7) owns dst g's 16 B o-slice: no cross-lane
// reduce. Indices staged once into LDS; inner loop consumes 8 via one
// ds_read_b128 and issues 8 independent dwordx4 gathers before the pmax block.
__global__ __launch_bounds__(256) void agg_kernel(
    const uint4* __restrict__ h, const int* __restrict__ cnt,
    const unsigned short* __restrict__ csr, float4* __restrict__ out) {
  __shared__ __align__(16) unsigned short sidx[32][136];  // 8704 B, row-padded
  const int bid = blockIdx.x;  // 5000 blocks = 625 grp x 8 phases
  const int p = bid & 7;
  const int grp = bid >> 3;
  const int n0 = grp * 32;
  const int tid = threadIdx.x;

  // stage 32 csr rows -> LDS (each thread copies 2x uint4 = 32 B, coalesced)
  {
    int r = tid >> 3;  // 0..31
    int q = tid & 7;   // 0..7
    const uint4* srow = (const uint4*)(csr + (size_t)(n0 + r) * CAPD);
    *(uint4*)&sidx[r][q * 8] = srow[q];
    *(uint4*)&sidx[r][(q + 8) * 8] = srow[q + 8];
  }
  __syncthreads();

  const int w = tid >> 6;
  const int lane = tid & 63;
  const int g = lane >> 3;       // dst slot within wave
  const int oq = lane & 7;       // o-pair slot (2 o x 4 t = 16 B)
  const int n = n0 + w * 8 + g;  // this lane's dst

  int deg = cnt[n * CNTSTRIDE];
  deg = deg > CAPD ? CAPD : deg;

  const unsigned short* myrow = sidx[w * 8 + g];
  int idx0 = (deg > 0) ? (int)myrow[0] : 0;  // clamp target (valid & L1-hot)

  // wave-max of deg (uniform loop bound; clamped lanes load dups)
  int dmax = deg;
#pragma unroll
  for (int d = 8; d <= 32; d <<= 1) {
    int o = __shfl_xor(dmax, d);
    dmax = o > dmax ? o : dmax;
  }
  dmax = __builtin_amdgcn_readfirstlane(dmax);

  unsigned a0 = 0x007F007Fu, a1 = a0, a2 = a0, a3 = a0;  // enc(-inf) packed
  const char* hb = (const char*)h;
  const unsigned pb = (((unsigned)p * 8 + oq) << 4);  // byte offset within h row

  for (int jb = 0; jb < dmax; jb += 8) {
    uint4 iv = *(const uint4*)&myrow[jb];  // ds_read_b128: 8 indices, broadcast
    int e0 = (int)(iv.x & 0xFFFFu), e1 = (int)(iv.x >> 16);
    int e2 = (int)(iv.y & 0xFFFFu), e3 = (int)(iv.y >> 16);
    int e4 = (int)(iv.z & 0xFFFFu), e5 = (int)(iv.z >> 16);
    int e6 = (int)(iv.w & 0xFFFFu), e7 = (int)(iv.w >> 16);
    e0 = (jb + 0 < deg) ? e0 : idx0;
    e1 = (jb + 1 < deg) ? e1 : idx0;
    e2 = (jb + 2 < deg) ? e2 : idx0;
    e3 = (jb + 3 < deg) ? e3 : idx0;
    e4 = (jb + 4 < deg) ? e4 : idx0;
    e5 = (jb + 5 < deg) ? e5 : idx0;
    e6 = (jb + 6 < deg) ? e6 : idx0;
    e7 = (jb + 7 < deg) ? e7 : idx0;
    uint4 v0 = *(const uint4*)(hb + (((unsigned)e0 << 10) + pb));
    uint4 v1 = *(const uint4*)(hb + (((unsigned)e1 << 10) + pb));
    uint4 v2 = *(const uint4*)(hb + (((unsigned)e2 << 10) + pb));
    uint4 v3 = *(const uint4*)(hb + (((unsigned)e3 << 10) + pb));
    uint4 v4 = *(const uint4*)(hb + (((unsigned)e4 << 10) + pb));
    uint4 v5 = *(const uint4*)(hb + (((unsigned)e5 << 10) + pb));
    uint4 v6 = *(const uint4*)(hb + (((unsigned)e6 << 10) + pb));
    uint4 v7 = *(const uint4*)(hb + (((unsigned)e7 << 10) + pb));
    PMX4(v0); PMX4(v1); PMX4(v2); PMX4(v3);
    PMX4(v4); PMX4(v5); PMX4(v6); PMX4(v7);
  }

  float4 o0, o1;
  if (deg == 0) {
    o0 = make_float4(0.f, 0.f, 0.f, 0.f);
    o1 = o0;
  } else {
    o0 = make_float4(dec16(a0 & 0xFFFFu), dec16(a0 >> 16),
                     dec16(a1 & 0xFFFFu), dec16(a1 >> 16));
    o1 = make_float4(dec16(a2 & 0xFFFFu), dec16(a2 >> 16),
                     dec16(a3 & 0xFFFFu), dec16(a3 >> 16));
  }
  out[(size_t)n * 128 + p * 16 + oq * 2] = o0;
  out[(size_t)n * 128 + p * 16 + oq * 2 + 1] = o1;
}

// ---------- launcher ----------
extern "C" void kernel_launch(void* const* d_in, const int* in_sizes, int n_in,
                              void* d_out, int out_size, void* d_ws, size_t ws_size,
                              hipStream_t stream) {
  const float* x = (const float*)d_in[0];
  const int* ei = (const int*)d_in[1];
  const float* W = (const float*)d_in[2];
  const float* b = (const float*)d_in[3];
  float* out = (float*)d_out;

  char* ws = (char*)d_ws;
  uint4* h = (uint4*)ws;                                   // 20,480,000 B
  int* cnt = (int*)(ws + 20480000);                        // 20,000 x 16 x 4 = 1,280,000 B
  unsigned short* csr = (unsigned short*)(ws + 21760000);  // 20000*128*2 = 5,120,000 B
  unsigned short* Wbf = (unsigned short*)(ws + 26880000);  // 32,768 B

  init_kernel<<<(N_NODES * CNTSTRIDE + 255) / 256, 256, 0, stream>>>(W, Wbf, cnt);
  gemm_scatter_kernel<<<N_NODES / 16, 512, 0, stream>>>((const float4*)x, Wbf, b, h,
                                                        ei, cnt, csr);
  agg_kernel<<<(N_NODES / 32) * NPHASE, 256, 0, stream>>>(h, cnt, csr, (float4*)out);
}

// Round 9
// 168.195 us; speedup vs baseline: 1.1641x; 1.0736x over previous
//
#include <hip/hip_runtime.h>
#include <hip/hip_bf16.h>
#include <stdint.h>

#define N_NODES 20000
#define N_EDGES 640000
#define FEAT 128
#define CAPD 128      // per-dst list cap; deg ~ Poisson(32), P(>128) ~ 1e-43
#define NPHASE 8      // o-feature slices of 16 (2.56 MB h-slice, L2-resident per XCD)
#define CNTSTRIDE 16  // one counter per 64B line

typedef __attribute__((ext_vector_type(8))) short bf16x8;
typedef __attribute__((ext_vector_type(4))) float f32x4;

// ---------- helpers ----------
// packed f32x2 -> bf16x2 (v_cvt_pk_bf16_f32), lo in low half
__device__ __forceinline__ unsigned pkbf16(float lo, float hi) {
  __hip_bfloat162 p = __float22bfloat162_rn(make_float2(lo, hi));
  return *reinterpret_cast<unsigned*>(&p);
}

// order-preserving encode: f32 -> RNE-rounded bf16 -> monotone u16
__device__ __forceinline__ unsigned short enc16(float f) {
  unsigned a = __float_as_uint(f);
  unsigned b = (a + 0x7FFFu + ((a >> 16) & 1u)) >> 16;  // RNE to bf16
  unsigned s = (unsigned)((int)a >> 31);                // 0 or ~0
  return (unsigned short)((b ^ 0x8000u) ^ (s & 0x7FFFu));
}

// inverse of enc16 (result as f32)
__device__ __forceinline__ float dec16(unsigned e) {
  unsigned b = (e & 0x8000u) ? (e ^ 0x8000u) : (e ^ 0xFFFFu);
  return __uint_as_float(b << 16);
}

// packed 2x u16 max
__device__ __forceinline__ void pmax(unsigned& a, unsigned v) {
  asm("v_pk_max_u16 %0, %0, %1" : "+v"(a) : "v"(v));
}

#define PMX4(v)                                              \
  do {                                                       \
    pmax(a0, (v).x); pmax(a1, (v).y);                        \
    pmax(a2, (v).z); pmax(a3, (v).w);                        \
  } while (0)

// ---------- kernel 1: zero padded cnt + convert W -> bf16 ([o][f] layout) ----------
__global__ void init_kernel(const float* __restrict__ W,
                            unsigned short* __restrict__ Wbf,
                            int* __restrict__ cnt) {
  int i = blockIdx.x * 256 + threadIdx.x;
  if (i < N_NODES * CNTSTRIDE) cnt[i] = 0;
  if (i < FEAT * FEAT / 2) {
    float2 w = ((const float2*)W)[i];
    ((unsigned*)Wbf)[i] = pkbf16(w.x, w.y);
  }
}

// ---------- kernel 2: grid-specialized scatter/GEMM, one dispatch ----------
// bid%3==2  -> pure scatter block: 1024 edges, no barriers, tiny VGPR. The CU
//              scheduler co-resides these with gemm blocks; 320K threads of
//              pure TLP hide the ~900cy atomic round-trips.
// bid%3<2   -> pure GEMM block (16-node tile): no atomics in its vmcnt queue,
//              8 waves ALL doing MFMA (wave = (t, os-half): 4 os each).
__global__ __launch_bounds__(512) void gemm_scatter_kernel(
    const float4* __restrict__ x, const unsigned short* __restrict__ Wbf,
    const float* __restrict__ b, uint4* __restrict__ h,
    const int* __restrict__ ei, int* __restrict__ cnt,
    unsigned short* __restrict__ csr) {
  // x-stage: [t][16 n][136 f] bf16 = 17408 B.  h-stage (aliased): [16 n][520] u16.
  __shared__ __align__(16) unsigned short sm[17408 / 2];
  const int tid = threadIdx.x;  // 0..511
  const int bid = blockIdx.x;
  const int m3 = bid % 3;

  if (m3 == 2) {
    // ---- pure scatter block: 1024 edges ----
    const int base = (bid / 3) * 1024;
#pragma unroll
    for (int r = 0; r < 2; ++r) {
      int e = base + r * 512 + tid;
      int src = ei[e];
      int dst = ei[N_EDGES + e];
      int pos = atomicAdd(&cnt[dst * CNTSTRIDE], 1);
      if (pos < CAPD) csr[(size_t)dst * CAPD + pos] = (unsigned short)src;
    }
    return;
  }

  // ---- pure GEMM block ----
  const int tile = (bid / 3) * 2 + m3;  // 0..1249
  const int n0 = tile * 16;

  // staging loads: 4x float4 per thread (2 f-pair units)
  const int e0 = tid, e1 = tid + 512;
  const int na = e0 >> 6, fa = e0 & 63;
  const int nb = e1 >> 6, fb = e1 & 63;
  float4 a0 = x[(size_t)(n0 + na) * 128 + 2 * fa];
  float4 c0 = x[(size_t)(n0 + na) * 128 + 2 * fa + 1];
  float4 a1 = x[(size_t)(n0 + nb) * 128 + 2 * fb];
  float4 c1 = x[(size_t)(n0 + nb) * 128 + 2 * fb + 1];

  ((unsigned*)sm)[(0 * 16 + na) * 68 + fa] = pkbf16(a0.x, c0.x);
  ((unsigned*)sm)[(1 * 16 + na) * 68 + fa] = pkbf16(a0.y, c0.y);
  ((unsigned*)sm)[(2 * 16 + na) * 68 + fa] = pkbf16(a0.z, c0.z);
  ((unsigned*)sm)[(3 * 16 + na) * 68 + fa] = pkbf16(a0.w, c0.w);
  ((unsigned*)sm)[(0 * 16 + nb) * 68 + fb] = pkbf16(a1.x, c1.x);
  ((unsigned*)sm)[(1 * 16 + nb) * 68 + fb] = pkbf16(a1.y, c1.y);
  ((unsigned*)sm)[(2 * 16 + nb) * 68 + fb] = pkbf16(a1.z, c1.z);
  ((unsigned*)sm)[(3 * 16 + nb) * 68 + fb] = pkbf16(a1.w, c1.w);

  __syncthreads();

  const int wv = tid >> 6;   // 8 waves
  const int l = tid & 63;
  const int col = l & 15;
  const int quad = l >> 4;
  const int t = wv & 3;      // t-slice
  const int osh = wv >> 2;   // os half: 0 -> os 0..3, 1 -> os 4..7

  f32x4 acc[4];
#pragma unroll
  for (int os = 0; os < 4; ++os) {
    float bv = b[(osh * 4 + os) * 16 + col];
    acc[os] = (f32x4){bv, bv, bv, bv};
  }

#pragma unroll
  for (int k = 0; k < 4; ++k) {
    bf16x8 af = *(const bf16x8*)&sm[(t * 16 + col) * 136 + k * 32 + quad * 8];
#pragma unroll
    for (int os = 0; os < 4; ++os) {
      bf16x8 bfv =
          *(const bf16x8*)&Wbf[((osh * 4 + os) * 16 + col) * 128 + k * 32 + quad * 8];
      acc[os] = __builtin_amdgcn_mfma_f32_16x16x32_bf16(af, bfv, acc[os], 0, 0, 0);
    }
  }

  __syncthreads();

  // C layout: D[m = quad*4 + r][o = (osh*4+os)*16 + col]; h-stage [n][o][t], row 520.
#pragma unroll
  for (int os = 0; os < 4; ++os) {
#pragma unroll
    for (int r = 0; r < 4; ++r) {
      sm[(quad * 4 + r) * 520 + ((osh * 4 + os) * 16 + col) * 4 + t] = enc16(acc[os][r]);
    }
  }
  __syncthreads();

  // h-write: 2 uint4 per thread across all 8 waves
#pragma unroll
  for (int it = 0; it < 2; ++it) {
    int e = tid + it * 512;
    int n = e >> 6, q = e & 63;
    uint4 v = *(const uint4*)&sm[n * 520 + q * 8];
    h[(size_t)(n0 + n) * 64 + q] = v;
  }
}

// ---------- kernel 3: o-phased agg (R6 body), 8 dsts/wave, LDS-staged idx ----------
// phase = blockIdx.x & 7 == XCD: 2.56 MB h-slice stays L2-resident per XCD.
// Lane (g = lane>>3, oq = lane&7) owns dst g's 16 B o-slice: no cross-lane
// reduce. Indices staged once into LDS; inner loop consumes 8 via one
// ds_read_b128 and issues 8 independent dwordx4 gathers before the pmax block.
__global__ __launch_bounds__(256) void agg_kernel(
    const uint4* __restrict__ h, const int* __restrict__ cnt,
    const unsigned short* __restrict__ csr, float4* __restrict__ out) {
  __shared__ __align__(16) unsigned short sidx[32][136];  // 8704 B, row-padded
  const int bid = blockIdx.x;  // 5000 blocks = 625 grp x 8 phases
  const int p = bid & 7;
  const int grp = bid >> 3;
  const int n0 = grp * 32;
  const int tid = threadIdx.x;

  // stage 32 csr rows -> LDS (each thread copies 2x uint4 = 32 B, coalesced)
  {
    int r = tid >> 3;  // 0..31
    int q = tid & 7;   // 0..7
    const uint4* srow = (const uint4*)(csr + (size_t)(n0 + r) * CAPD);
    *(uint4*)&sidx[r][q * 8] = srow[q];
    *(uint4*)&sidx[r][(q + 8) * 8] = srow[q + 8];
  }
  __syncthreads();

  const int w = tid >> 6;
  const int lane = tid & 63;
  const int g = lane >> 3;       // dst slot within wave
  const int oq = lane & 7;       // o-pair slot (2 o x 4 t = 16 B)
  const int n = n0 + w * 8 + g;  // this lane's dst

  int deg = cnt[n * CNTSTRIDE];
  deg = deg > CAPD ? CAPD : deg;

  const unsigned short* myrow = sidx[w * 8 + g];
  int idx0 = (deg > 0) ? (int)myrow[0] : 0;  // clamp target (valid & L1-hot)

  // wave-max of deg (uniform loop bound; clamped lanes load dups)
  int dmax = deg;
#pragma unroll
  for (int d = 8; d <= 32; d <<= 1) {
    int o = __shfl_xor(dmax, d);
    dmax = o > dmax ? o : dmax;
  }
  dmax = __builtin_amdgcn_readfirstlane(dmax);

  unsigned a0 = 0x007F007Fu, a1 = a0, a2 = a0, a3 = a0;  // enc(-inf) packed
  const char* hb = (const char*)h;
  const unsigned pb = (((unsigned)p * 8 + oq) << 4);  // byte offset within h row

  for (int jb = 0; jb < dmax; jb += 8) {
    uint4 iv = *(const uint4*)&myrow[jb];  // ds_read_b128: 8 indices, broadcast
    int e0 = (int)(iv.x & 0xFFFFu), e1 = (int)(iv.x >> 16);
    int e2 = (int)(iv.y & 0xFFFFu), e3 = (int)(iv.y >> 16);
    int e4 = (int)(iv.z & 0xFFFFu), e5 = (int)(iv.z >> 16);
    int e6 = (int)(iv.w & 0xFFFFu), e7 = (int)(iv.w >> 16);
    e0 = (jb + 0 < deg) ? e0 : idx0;
    e1 = (jb + 1 < deg) ? e1 : idx0;
    e2 = (jb + 2 < deg) ? e2 : idx0;
    e3 = (jb + 3 < deg) ? e3 : idx0;
    e4 = (jb + 4 < deg) ? e4 : idx0;
    e5 = (jb + 5 < deg) ? e5 : idx0;
    e6 = (jb + 6 < deg) ? e6 : idx0;
    e7 = (jb + 7 < deg) ? e7 : idx0;
    uint4 v0 = *(const uint4*)(hb + (((unsigned)e0 << 10) + pb));
    uint4 v1 = *(const uint4*)(hb + (((unsigned)e1 << 10) + pb));
    uint4 v2 = *(const uint4*)(hb + (((unsigned)e2 << 10) + pb));
    uint4 v3 = *(const uint4*)(hb + (((unsigned)e3 << 10) + pb));
    uint4 v4 = *(const uint4*)(hb + (((unsigned)e4 << 10) + pb));
    uint4 v5 = *(const uint4*)(hb + (((unsigned)e5 << 10) + pb));
    uint4 v6 = *(const uint4*)(hb + (((unsigned)e6 << 10) + pb));
    uint4 v7 = *(const uint4*)(hb + (((unsigned)e7 << 10) + pb));
    PMX4(v0); PMX4(v1); PMX4(v2); PMX4(v3);
    PMX4(v4); PMX4(v5); PMX4(v6); PMX4(v7);
  }

  float4 o0, o1;
  if (deg == 0) {
    o0 = make_float4(0.f, 0.f, 0.f, 0.f);
    o1 = o0;
  } else {
    o0 = make_float4(dec16(a0 & 0xFFFFu), dec16(a0 >> 16),
                     dec16(a1 & 0xFFFFu), dec16(a1 >> 16));
    o1 = make_float4(dec16(a2 & 0xFFFFu), dec16(a2 >> 16),
                     dec16(a3 & 0xFFFFu), dec16(a3 >> 16));
  }
  out[(size_t)n * 128 + p * 16 + oq * 2] = o0;
  out[(size_t)n * 128 + p * 16 + oq * 2 + 1] = o1;
}

// ---------- launcher ----------
extern "C" void kernel_launch(void* const* d_in, const int* in_sizes, int n_in,
                              void* d_out, int out_size, void* d_ws, size_t ws_size,
                              hipStream_t stream) {
  const float* x = (const float*)d_in[0];
  const int* ei = (const int*)d_in[1];
  const float* W = (const float*)d_in[2];
  const float* b = (const float*)d_in[3];
  float* out = (float*)d_out;

  char* ws = (char*)d_ws;
  uint4* h = (uint4*)ws;                                   // 20,480,000 B
  int* cnt = (int*)(ws + 20480000);                        // 20,000 x 16 x 4 = 1,280,000 B
  unsigned short* csr = (unsigned short*)(ws + 21760000);  // 20000*128*2 = 5,120,000 B
  unsigned short* Wbf = (unsigned short*)(ws + 26880000);  // 32,768 B

  init_kernel<<<(N_NODES * CNTSTRIDE + 255) / 256, 256, 0, stream>>>(W, Wbf, cnt);
  // 1875 blocks: 1250 gemm tiles (bid%3<2) + 625 scatter blocks (bid%3==2)
  gemm_scatter_kernel<<<1875, 512, 0, stream>>>((const float4*)x, Wbf, b, h,
                                                ei, cnt, csr);
  agg_kernel<<<(N_NODES / 32) * NPHASE, 256, 0, stream>>>(h, cnt, csr, (float4*)out);
}

// Round 10
// 164.239 us; speedup vs baseline: 1.1921x; 1.0241x over previous
//
#include <hip/hip_runtime.h>
#include <hip/hip_bf16.h>
#include <stdint.h>

#define N_NODES 20000
#define N_EDGES 640000
#define FEAT 128
#define CAPD 128      // per-dst list cap; deg ~ Poisson(32), P(>128) ~ 1e-43
#define NPHASE 8      // o-feature slices of 16 (2.56 MB h-slice, L2-resident per XCD)
#define CNTSTRIDE 16  // one counter per 64B line

typedef __attribute__((ext_vector_type(8))) short bf16x8;
typedef __attribute__((ext_vector_type(4))) float f32x4;

// ---------- helpers ----------
// packed f32x2 -> bf16x2 (v_cvt_pk_bf16_f32), lo in low half
__device__ __forceinline__ unsigned pkbf16(float lo, float hi) {
  __hip_bfloat162 p = __float22bfloat162_rn(make_float2(lo, hi));
  return *reinterpret_cast<unsigned*>(&p);
}

// order-preserving encode: f32 -> RNE-rounded bf16 -> monotone u16
__device__ __forceinline__ unsigned short enc16(float f) {
  unsigned a = __float_as_uint(f);
  unsigned b = (a + 0x7FFFu + ((a >> 16) & 1u)) >> 16;  // RNE to bf16
  unsigned s = (unsigned)((int)a >> 31);                // 0 or ~0
  return (unsigned short)((b ^ 0x8000u) ^ (s & 0x7FFFu));
}

// inverse of enc16 (result as f32)
__device__ __forceinline__ float dec16(unsigned e) {
  unsigned b = (e & 0x8000u) ? (e ^ 0x8000u) : (e ^ 0xFFFFu);
  return __uint_as_float(b << 16);
}

// packed 2x u16 max
__device__ __forceinline__ void pmax(unsigned& a, unsigned v) {
  asm("v_pk_max_u16 %0, %0, %1" : "+v"(a) : "v"(v));
}

#define PMX4(v)                                              \
  do {                                                       \
    pmax(a0, (v).x); pmax(a1, (v).y);                        \
    pmax(a2, (v).z); pmax(a3, (v).w);                        \
  } while (0)

// ---------- kernel 1: grid-specialized scatter/GEMM, one dispatch ----------
// bid%3==2  -> pure scatter block: 1024 edges, no barriers, tiny VGPR.
// bid%3<2   -> pure GEMM block (16-node tile): stages BOTH x and W into LDS
//              (W f32->bf16 per block; rows padded to 136 shorts => 2-way
//              conflicts only), 8 waves all doing MFMA (wave = (t, os-half)).
// cnt pre-zeroed by hipMemsetAsync; no init kernel, no global Wbf.
__global__ __launch_bounds__(512) void gemm_scatter_kernel(
    const float4* __restrict__ x, const float* __restrict__ W,
    const float* __restrict__ b, uint4* __restrict__ h,
    const int* __restrict__ ei, int* __restrict__ cnt,
    unsigned short* __restrict__ csr) {
  // x-stage: [t][16 n][136 f] = 17408 B (aliased by h-stage [16 n][520] u16).
  // W-stage: [128 o][136 f] bf16 = 34816 B.  Total 52224 B -> 3 blocks/CU.
  __shared__ __align__(16) unsigned short sm[17408 / 2];
  __shared__ __align__(16) unsigned short Wlds[128 * 136];
  const int tid = threadIdx.x;  // 0..511
  const int bid = blockIdx.x;
  const int m3 = bid % 3;

  if (m3 == 2) {
    // ---- pure scatter block: 1024 edges ----
    const int base = (bid / 3) * 1024;
#pragma unroll
    for (int r = 0; r < 2; ++r) {
      int e = base + r * 512 + tid;
      int src = ei[e];
      int dst = ei[N_EDGES + e];
      int pos = atomicAdd(&cnt[dst * CNTSTRIDE], 1);
      if (pos < CAPD) csr[(size_t)dst * CAPD + pos] = (unsigned short)src;
    }
    return;
  }

  // ---- pure GEMM block ----
  const int tile = (bid / 3) * 2 + m3;  // 0..1249
  const int n0 = tile * 16;

  // stage W -> LDS bf16: thread t converts 32 floats of row o = t>>2
  {
    const float4* Wv = (const float4*)W;
    const int o = tid >> 2;
    const int q0 = (tid & 3) * 8;  // float4 index within row
    float4 wa[8];
#pragma unroll
    for (int q = 0; q < 8; ++q) wa[q] = Wv[o * 32 + q0 + q];
    unsigned* wrow = (unsigned*)&Wlds[o * 136] + (tid & 3) * 16;
#pragma unroll
    for (int q = 0; q < 8; ++q) {
      wrow[2 * q] = pkbf16(wa[q].x, wa[q].y);
      wrow[2 * q + 1] = pkbf16(wa[q].z, wa[q].w);
    }
  }

  // staging loads: 4x float4 per thread (2 f-pair units)
  const int e0 = tid, e1 = tid + 512;
  const int na = e0 >> 6, fa = e0 & 63;
  const int nb = e1 >> 6, fb = e1 & 63;
  float4 a0 = x[(size_t)(n0 + na) * 128 + 2 * fa];
  float4 c0 = x[(size_t)(n0 + na) * 128 + 2 * fa + 1];
  float4 a1 = x[(size_t)(n0 + nb) * 128 + 2 * fb];
  float4 c1 = x[(size_t)(n0 + nb) * 128 + 2 * fb + 1];

  ((unsigned*)sm)[(0 * 16 + na) * 68 + fa] = pkbf16(a0.x, c0.x);
  ((unsigned*)sm)[(1 * 16 + na) * 68 + fa] = pkbf16(a0.y, c0.y);
  ((unsigned*)sm)[(2 * 16 + na) * 68 + fa] = pkbf16(a0.z, c0.z);
  ((unsigned*)sm)[(3 * 16 + na) * 68 + fa] = pkbf16(a0.w, c0.w);
  ((unsigned*)sm)[(0 * 16 + nb) * 68 + fb] = pkbf16(a1.x, c1.x);
  ((unsigned*)sm)[(1 * 16 + nb) * 68 + fb] = pkbf16(a1.y, c1.y);
  ((unsigned*)sm)[(2 * 16 + nb) * 68 + fb] = pkbf16(a1.z, c1.z);
  ((unsigned*)sm)[(3 * 16 + nb) * 68 + fb] = pkbf16(a1.w, c1.w);

  __syncthreads();

  const int wv = tid >> 6;  // 8 waves
  const int l = tid & 63;
  const int col = l & 15;
  const int quad = l >> 4;
  const int t = wv & 3;     // t-slice
  const int osh = wv >> 2;  // os half: 0 -> os 0..3, 1 -> os 4..7

  f32x4 acc[4];
#pragma unroll
  for (int os = 0; os < 4; ++os) {
    float bv = b[(osh * 4 + os) * 16 + col];
    acc[os] = (f32x4){bv, bv, bv, bv};
  }

#pragma unroll
  for (int k = 0; k < 4; ++k) {
    bf16x8 af = *(const bf16x8*)&sm[(t * 16 + col) * 136 + k * 32 + quad * 8];
#pragma unroll
    for (int os = 0; os < 4; ++os) {
      bf16x8 bfv =
          *(const bf16x8*)&Wlds[((osh * 4 + os) * 16 + col) * 136 + k * 32 + quad * 8];
      acc[os] = __builtin_amdgcn_mfma_f32_16x16x32_bf16(af, bfv, acc[os], 0, 0, 0);
    }
  }

  __syncthreads();

  // C layout: D[m = quad*4 + r][o = (osh*4+os)*16 + col]; h-stage [n][o][t], row 520.
#pragma unroll
  for (int os = 0; os < 4; ++os) {
#pragma unroll
    for (int r = 0; r < 4; ++r) {
      sm[(quad * 4 + r) * 520 + ((osh * 4 + os) * 16 + col) * 4 + t] = enc16(acc[os][r]);
    }
  }
  __syncthreads();

  // h-write: 2 uint4 per thread across all 8 waves
#pragma unroll
  for (int it = 0; it < 2; ++it) {
    int e = tid + it * 512;
    int n = e >> 6, q = e & 63;
    uint4 v = *(const uint4*)&sm[n * 520 + q * 8];
    h[(size_t)(n0 + n) * 64 + q] = v;
  }
}

// ---------- kernel 2: o-phased agg, 8 dsts/wave, LDS idx, ping-pong ILP-16 ----------
// phase = blockIdx.x & 7 == XCD: 2.56 MB h-slice stays L2-resident per XCD.
// Lane (g, oq) owns dst g's 16 B o-slice; indices staged in LDS. Inner loop
// ping-pongs two 8-load batches: issue B, pmax A, issue A', pmax B -- 8-16
// gathers in flight under every pmax block. NO occupancy cap (R7's mistake:
// (256,4) capped VGPR at 128 and strangled the double batch; R6's plain loop
// compiled to VGPR=28 = ~2 in flight). dmax rounded to 16; clamps to idx0.
#define CLAMP8(P, ivv, base)                                            \
  int P##0 = ((base) + 0 < deg) ? (int)((ivv).x & 0xFFFFu) : idx0;      \
  int P##1 = ((base) + 1 < deg) ? (int)((ivv).x >> 16) : idx0;          \
  int P##2 = ((base) + 2 < deg) ? (int)((ivv).y & 0xFFFFu) : idx0;      \
  int P##3 = ((base) + 3 < deg) ? (int)((ivv).y >> 16) : idx0;          \
  int P##4 = ((base) + 4 < deg) ? (int)((ivv).z & 0xFFFFu) : idx0;      \
  int P##5 = ((base) + 5 < deg) ? (int)((ivv).z >> 16) : idx0;          \
  int P##6 = ((base) + 6 < deg) ? (int)((ivv).w & 0xFFFFu) : idx0;      \
  int P##7 = ((base) + 7 < deg) ? (int)((ivv).w >> 16) : idx0;

#define ISSUE8(V, P)                                                    \
  V##0 = *(const uint4*)(hb + (((unsigned)P##0 << 10) + pb));           \
  V##1 = *(const uint4*)(hb + (((unsigned)P##1 << 10) + pb));           \
  V##2 = *(const uint4*)(hb + (((unsigned)P##2 << 10) + pb));           \
  V##3 = *(const uint4*)(hb + (((unsigned)P##3 << 10) + pb));           \
  V##4 = *(const uint4*)(hb + (((unsigned)P##4 << 10) + pb));           \
  V##5 = *(const uint4*)(hb + (((unsigned)P##5 << 10) + pb));           \
  V##6 = *(const uint4*)(hb + (((unsigned)P##6 << 10) + pb));           \
  V##7 = *(const uint4*)(hb + (((unsigned)P##7 << 10) + pb));

#define PMAX8(V)                                                        \
  do {                                                                  \
    PMX4(V##0); PMX4(V##1); PMX4(V##2); PMX4(V##3);                     \
    PMX4(V##4); PMX4(V##5); PMX4(V##6); PMX4(V##7);                     \
  } while (0)

__global__ __launch_bounds__(256) void agg_kernel(
    const uint4* __restrict__ h, const int* __restrict__ cnt,
    const unsigned short* __restrict__ csr, float4* __restrict__ out) {
  __shared__ __align__(16) unsigned short sidx[32][136];  // 8704 B, row-padded
  const int bid = blockIdx.x;  // 5000 blocks = 625 grp x 8 phases
  const int p = bid & 7;
  const int grp = bid >> 3;
  const int n0 = grp * 32;
  const int tid = threadIdx.x;

  // stage 32 csr rows -> LDS (each thread copies 2x uint4 = 32 B, coalesced)
  {
    int r = tid >> 3;  // 0..31
    int q = tid & 7;   // 0..7
    const uint4* srow = (const uint4*)(csr + (size_t)(n0 + r) * CAPD);
    *(uint4*)&sidx[r][q * 8] = srow[q];
    *(uint4*)&sidx[r][(q + 8) * 8] = srow[q + 8];
  }
  __syncthreads();

  const int w = tid >> 6;
  const int lane = tid & 63;
  const int g = lane >> 3;       // dst slot within wave
  const int oq = lane & 7;       // o-pair slot (2 o x 4 t = 16 B)
  const int n = n0 + w * 8 + g;  // this lane's dst

  int deg = cnt[n * CNTSTRIDE];
  deg = deg > CAPD ? CAPD : deg;

  const unsigned short* myrow = sidx[w * 8 + g];
  int idx0 = (deg > 0) ? (int)myrow[0] : 0;  // clamp target (valid & L1-hot)

  // wave-max of deg (uniform loop bound; clamped lanes load dups)
  int dmax = deg;
#pragma unroll
  for (int d = 8; d <= 32; d <<= 1) {
    int o = __shfl_xor(dmax, d);
    dmax = o > dmax ? o : dmax;
  }
  dmax = __builtin_amdgcn_readfirstlane(dmax);

  unsigned a0 = 0x007F007Fu, a1 = a0, a2 = a0, a3 = a0;  // enc(-inf) packed
  const char* hb = (const char*)h;
  const unsigned pb = (((unsigned)p * 8 + oq) << 4);  // byte offset within h row

  if (dmax > 0) {
    const int dmax16 = (dmax + 15) & ~15;  // 16..128
    uint4 vA0, vA1, vA2, vA3, vA4, vA5, vA6, vA7;
    uint4 vB0, vB1, vB2, vB3, vB4, vB5, vB6, vB7;
    {
      uint4 iv = *(const uint4*)&myrow[0];
      CLAMP8(eA, iv, 0);
      ISSUE8(vA, eA);
    }
    int jb = 0;
    while (true) {
      {
        uint4 iv = *(const uint4*)&myrow[jb + 8];
        CLAMP8(eB, iv, jb + 8);
        ISSUE8(vB, eB);
      }
      PMAX8(vA);
      jb += 16;
      if (jb >= dmax16) {
        PMAX8(vB);
        break;
      }
      {
        uint4 iv = *(const uint4*)&myrow[jb];
        CLAMP8(eA2, iv, jb);
        ISSUE8(vA, eA2);
      }
      PMAX8(vB);
    }
  }

  float4 o0, o1;
  if (deg == 0) {
    o0 = make_float4(0.f, 0.f, 0.f, 0.f);
    o1 = o0;
  } else {
    o0 = make_float4(dec16(a0 & 0xFFFFu), dec16(a0 >> 16),
                     dec16(a1 & 0xFFFFu), dec16(a1 >> 16));
    o1 = make_float4(dec16(a2 & 0xFFFFu), dec16(a2 >> 16),
                     dec16(a3 & 0xFFFFu), dec16(a3 >> 16));
  }
  out[(size_t)n * 128 + p * 16 + oq * 2] = o0;
  out[(size_t)n * 128 + p * 16 + oq * 2 + 1] = o1;
}

// ---------- launcher ----------
extern "C" void kernel_launch(void* const* d_in, const int* in_sizes, int n_in,
                              void* d_out, int out_size, void* d_ws, size_t ws_size,
                              hipStream_t stream) {
  const float* x = (const float*)d_in[0];
  const int* ei = (const int*)d_in[1];
  const float* W = (const float*)d_in[2];
  const float* b = (const float*)d_in[3];
  float* out = (float*)d_out;

  char* ws = (char*)d_ws;
  uint4* h = (uint4*)ws;                                   // 20,480,000 B
  int* cnt = (int*)(ws + 20480000);                        // 20,000 x 16 x 4 = 1,280,000 B
  unsigned short* csr = (unsigned short*)(ws + 21760000);  // 20000*128*2 = 5,120,000 B

  hipMemsetAsync(cnt, 0, N_NODES * CNTSTRIDE * sizeof(int), stream);
  // 1875 blocks: 1250 gemm tiles (bid%3<2) + 625 scatter blocks (bid%3==2)
  gemm_scatter_kernel<<<1875, 512, 0, stream>>>((const float4*)x, W, b, h,
                                                ei, cnt, csr);
  agg_kernel<<<(N_NODES / 32) * NPHASE, 256, 0, stream>>>(h, cnt, csr, (float4*)out);
}